// Round 2
// baseline (492.996 us; speedup 1.0000x reference)
//
#include <hip/hip_runtime.h>

#define B_   8
#define N_   307
#define BN   (B_ * N_)           // 2456 blocks
#define OUT_ELEMS (BN * 64 * 64) // out floats; scores follow in d_out

typedef float f32x4 __attribute__((ext_vector_type(4)));
typedef short s16x8 __attribute__((ext_vector_type(8)));

__device__ __forceinline__ unsigned short f2bf(float x) {
    unsigned int u = __builtin_bit_cast(unsigned int, x);
    u += 0x7FFFu + ((u >> 16) & 1u);        // round-to-nearest-even
    return (unsigned short)(u >> 16);
}

// ---- prep kernel: convert Wq/Wk/Wv/Wfc (64x64 fp32 row-major, K x N) into
// bf16 B-operand fragment layout in d_ws: [mat][ (nt*2+ki)*64 + lane ][8]
// B element (k,n): ki=k>>5, lane=((k>>3)&3)*16+(n&15), j=k&7
__global__ void prep_w(const float* __restrict__ Wq, const float* __restrict__ Wk,
                       const float* __restrict__ Wv, const float* __restrict__ Wfc,
                       unsigned short* __restrict__ wf) {
    const float* Ws = (blockIdx.x == 0) ? Wq : (blockIdx.x == 1) ? Wk
                    : (blockIdx.x == 2) ? Wv : Wfc;
    unsigned short* dst = wf + blockIdx.x * 4096;
    const float4* s4 = (const float4*)Ws;
    int tid = threadIdx.x;
#pragma unroll
    for (int i = 0; i < 4; ++i) {
        int idx = i * 256 + tid;           // 1024 float4
        float4 v = s4[idx];
        int k  = idx >> 4;
        int n0 = (idx & 15) << 2;
        float vv[4] = {v.x, v.y, v.z, v.w};
#pragma unroll
        for (int c = 0; c < 4; ++c) {
            int n = n0 + c;
            dst[((((n >> 4) * 2 + (k >> 5)) * 64 + (((k >> 3) & 3) << 4) + (n & 15)) << 3)
                + (k & 7)] = f2bf(vv[c]);
        }
    }
}

__global__ __launch_bounds__(256, 4) void mta_kernel(
    const float* __restrict__ Xq, const float* __restrict__ Xk,
    const float* __restrict__ Xv, const float* __restrict__ maskp,
    const float* __restrict__ res, const unsigned short* __restrict__ wfrag,
    const float* __restrict__ lnS, const float* __restrict__ lnB,
    float* __restrict__ out, float* __restrict__ scores_out)
{
    // LDS 40KB: sQf[0,8K) sKf[8K,16K) sVf[16K,24K) free[24K,40K)
    // attn transpose bufs (8K/wave): w0->0, w1->8K, w2->24K, w3->32K (sVf preserved)
    // ctx frags after PV barrier -> [0,8K)
    __shared__ __align__(16) unsigned char smem[40960];
    unsigned short* sQf = (unsigned short*)smem;            // [h][mt][32][8] (quads 0-1)
    unsigned short* sKf = (unsigned short*)(smem + 8192);   // [h][nt][32][8]
    unsigned short* sVf = (unsigned short*)(smem + 16384);  // [h][ki][64][8]

    const int bn   = blockIdx.x;
    const int tid  = threadIdx.x;
    const int w    = tid >> 6;        // wave id = row-tile (proj/fc) = head (attn)
    const int lane = tid & 63;
    const int quad = lane >> 4;
    const int l16  = lane & 15;
    const size_t base64 = (size_t)bn * 4096;

    // ---------------- Projections (barrier-free): wave w does rows w*16..+15 ----
#pragma unroll 1
    for (int pj = 0; pj < 3; ++pj) {
        const float* Xs = (pj == 0) ? Xq : (pj == 1) ? Xk : Xv;
        const unsigned short* wb = wfrag + pj * 4096;
        // A-frags straight from global (coalesced float4 pairs)
        s16x8 a[2];
#pragma unroll
        for (int ki = 0; ki < 2; ++ki) {
            const float* rp = Xs + base64 + (w * 16 + l16) * 64 + ki * 32 + quad * 8;
            float4 lo = *(const float4*)rp;
            float4 hi = *(const float4*)(rp + 4);
            s16x8 t;
            t[0] = (short)f2bf(lo.x); t[1] = (short)f2bf(lo.y);
            t[2] = (short)f2bf(lo.z); t[3] = (short)f2bf(lo.w);
            t[4] = (short)f2bf(hi.x); t[5] = (short)f2bf(hi.y);
            t[6] = (short)f2bf(hi.z); t[7] = (short)f2bf(hi.w);
            a[ki] = t;
        }
#pragma unroll
        for (int nt = 0; nt < 4; ++nt) {
            s16x8 b0 = *(const s16x8*)(wb + (((nt * 2 + 0) * 64 + lane) << 3));
            s16x8 b1 = *(const s16x8*)(wb + (((nt * 2 + 1) * 64 + lane) << 3));
            f32x4 acc = {0.f, 0.f, 0.f, 0.f};
            acc = __builtin_amdgcn_mfma_f32_16x16x32_bf16(a[0], b0, acc, 0, 0, 0);
            acc = __builtin_amdgcn_mfma_f32_16x16x32_bf16(a[1], b1, acc, 0, 0, 0);
            // writeback: element (row = w*16+quad*4+r, col = nt*16+l16)
            if (pj == 0) {          // Q -> scores A-frags, fold 1/sqrt(D_K)
#pragma unroll
                for (int r = 0; r < 4; ++r)
                    sQf[(((nt * 4 + w) * 32 + ((l16 >> 3) << 4) + quad * 4 + r) << 3)
                        + (l16 & 7)] = f2bf(acc[r] * 0.25f);
            } else if (pj == 1) {   // K -> scores B-frags
#pragma unroll
                for (int r = 0; r < 4; ++r)
                    sKf[(((nt * 4 + w) * 32 + ((l16 >> 3) << 4) + quad * 4 + r) << 3)
                        + (l16 & 7)] = f2bf(acc[r]);
            } else {                // V -> PV B-frags
#pragma unroll
                for (int r = 0; r < 4; ++r) {
                    int kk = w * 16 + quad * 4 + r;
                    sVf[(((nt * 2 + (kk >> 5)) * 64 + (((kk >> 3) & 3) << 4) + l16) << 3)
                        + (kk & 7)] = f2bf(acc[r]);
                }
            }
        }
    }
    __syncthreads();   // #1: QKV frags visible to all waves

    // ---------------- Attention: wave w owns head h = w ----------------
    const int h = w;
    const s16x8 zf = {0, 0, 0, 0, 0, 0, 0, 0};
    s16x8 aq[4], bk[4];
#pragma unroll
    for (int mt = 0; mt < 4; ++mt)
        aq[mt] = (lane < 32) ? *(const s16x8*)(sQf + (((h * 4 + mt) * 32 + lane) << 3)) : zf;
#pragma unroll
    for (int nt = 0; nt < 4; ++nt)
        bk[nt] = (lane < 32) ? *(const s16x8*)(sKf + (((h * 4 + nt) * 32 + lane) << 3)) : zf;
    __syncthreads();   // #2: sQf/sKf free for attn transpose buffers

    f32x4 sacc[4][4];
#pragma unroll
    for (int nt = 0; nt < 4; ++nt)
#pragma unroll
        for (int mt = 0; mt < 4; ++mt) {
            f32x4 t = {0.f, 0.f, 0.f, 0.f};
            sacc[mt][nt] = __builtin_amdgcn_mfma_f32_16x16x32_bf16(aq[mt], bk[nt], t, 0, 0, 0);
        }

    // row masks (q-dependent only; broadcast across l16 lanes)
    float mrow[4][4];
#pragma unroll
    for (int mt = 0; mt < 4; ++mt)
#pragma unroll
        for (int r = 0; r < 4; ++r)
            mrow[mt][r] = maskp[bn * 64 + mt * 16 + quad * 4 + r];

    // scores = QK + res, mask, write to global, keep in regs
    const float* rb = res + (((size_t)(bn * 4 + h)) << 12);
    float* so = scores_out + (((size_t)(bn * 4 + h)) << 12);
#pragma unroll
    for (int mt = 0; mt < 4; ++mt)
#pragma unroll
        for (int nt = 0; nt < 4; ++nt)
#pragma unroll
            for (int r = 0; r < 4; ++r) {
                int off = (mt * 16 + quad * 4 + r) * 64 + nt * 16 + l16;
                float s = sacc[mt][nt][r] + rb[off];
                s = (mrow[mt][r] > 0.5f) ? -1e9f : s;
                so[off] = s;
                sacc[mt][nt][r] = s;
            }

    // column softmax over q (per column: 16 in-lane values + quads via xor 16,32)
    float inv_[4];
#pragma unroll
    for (int nt = 0; nt < 4; ++nt) {
        float m = -3.0e38f;
#pragma unroll
        for (int mt = 0; mt < 4; ++mt)
#pragma unroll
            for (int r = 0; r < 4; ++r) m = fmaxf(m, sacc[mt][nt][r]);
        m = fmaxf(m, __shfl_xor(m, 16, 64));
        m = fmaxf(m, __shfl_xor(m, 32, 64));
        float ss = 0.f;
#pragma unroll
        for (int mt = 0; mt < 4; ++mt)
#pragma unroll
            for (int r = 0; r < 4; ++r) {
                float e = __expf(sacc[mt][nt][r] - m);
                sacc[mt][nt][r] = e;
                ss += e;
            }
        ss += __shfl_xor(ss, 16, 64);
        ss += __shfl_xor(ss, 32, 64);
        inv_[nt] = 1.0f / ss;
    }

    // attn -> per-wave private A-frag transpose buffer (no barrier needed)
    unsigned short* sAt = (unsigned short*)(smem + w * 8192 + ((w >= 2) ? 8192 : 0));
#pragma unroll
    for (int mt = 0; mt < 4; ++mt)
#pragma unroll
        for (int nt = 0; nt < 4; ++nt)
#pragma unroll
            for (int r = 0; r < 4; ++r) {
                int kat = nt * 16 + l16;
                float a = sacc[mt][nt][r] * inv_[nt];
                sAt[(((mt * 2 + (kat >> 5)) * 64 + (((kat >> 3) & 3) << 4) + quad * 4 + r) << 3)
                    + (kat & 7)] = f2bf(a);
            }

    // PV: ctx_h[mt] = attn · V_h
    f32x4 ctx[4];
#pragma unroll
    for (int mt = 0; mt < 4; ++mt) {
        f32x4 c = {0.f, 0.f, 0.f, 0.f};
#pragma unroll
        for (int ki = 0; ki < 2; ++ki) {
            s16x8 ap = *(const s16x8*)(sAt + (((mt * 2 + ki) * 64 + lane) << 3));
            s16x8 bv = *(const s16x8*)(sVf + (((h * 2 + ki) * 64 + lane) << 3));
            c = __builtin_amdgcn_mfma_f32_16x16x32_bf16(ap, bv, c, 0, 0, 0);
        }
        ctx[mt] = c;
    }
    __syncthreads();   // #3: all PV done; LDS free

    // ---------------- fc + residual + layernorm ----------------
    // ctx element (q = mt*16+quad*4+r, c = h*16+l16) -> A-frag layout at smem[0,8K)
    unsigned short* sCf = (unsigned short*)smem;
#pragma unroll
    for (int mt = 0; mt < 4; ++mt)
#pragma unroll
        for (int r = 0; r < 4; ++r)
            sCf[(((mt * 2 + (h >> 1)) * 64 + (((h * 2 + (l16 >> 3)) & 3) << 4) + quad * 4 + r)
                 << 3) + (l16 & 7)] = f2bf(ctx[mt][r]);
    __syncthreads();   // #4

    const unsigned short* wfc = wfrag + 3 * 4096;
    s16x8 a0 = *(const s16x8*)(sCf + (((w * 2 + 0) * 64 + lane) << 3));
    s16x8 a1 = *(const s16x8*)(sCf + (((w * 2 + 1) * 64 + lane) << 3));
    f32x4 oacc[4];
#pragma unroll
    for (int nt = 0; nt < 4; ++nt) {
        s16x8 b0 = *(const s16x8*)(wfc + (((nt * 2 + 0) * 64 + lane) << 3));
        s16x8 b1 = *(const s16x8*)(wfc + (((nt * 2 + 1) * 64 + lane) << 3));
        f32x4 acc = {0.f, 0.f, 0.f, 0.f};
        acc = __builtin_amdgcn_mfma_f32_16x16x32_bf16(a0, b0, acc, 0, 0, 0);
        acc = __builtin_amdgcn_mfma_f32_16x16x32_bf16(a1, b1, acc, 0, 0, 0);
        oacc[nt] = acc;
    }

    float scl[4], bia[4];
#pragma unroll
    for (int nt = 0; nt < 4; ++nt) {
        scl[nt] = lnS[nt * 16 + l16];
        bia[nt] = lnB[nt * 16 + l16];
    }
#pragma unroll
    for (int r = 0; r < 4; ++r) {
        int q = w * 16 + quad * 4 + r;
        float px[4], sum = 0.f, sq = 0.f;
#pragma unroll
        for (int nt = 0; nt < 4; ++nt) {
            float x = oacc[nt][r] + Xq[base64 + q * 64 + nt * 16 + l16];
            px[nt] = x; sum += x; sq += x * x;
        }
#pragma unroll
        for (int m = 1; m <= 8; m <<= 1) {
            sum += __shfl_xor(sum, m, 64);
            sq  += __shfl_xor(sq,  m, 64);
        }
        float mu   = sum * 0.015625f;
        float var  = sq * 0.015625f - mu * mu;
        float rstd = rsqrtf(var + 1e-5f);
#pragma unroll
        for (int nt = 0; nt < 4; ++nt)
            out[base64 + q * 64 + nt * 16 + l16] = (px[nt] - mu) * rstd * scl[nt] + bia[nt];
    }
}

extern "C" void kernel_launch(void* const* d_in, const int* in_sizes, int n_in,
                              void* d_out, int out_size, void* d_ws, size_t ws_size,
                              hipStream_t stream) {
    const float* Xq   = (const float*)d_in[0];
    const float* Xk   = (const float*)d_in[1];
    const float* Xv   = (const float*)d_in[2];
    const float* msk  = (const float*)d_in[3];
    const float* res  = (const float*)d_in[4];
    const float* Wq   = (const float*)d_in[5];
    const float* Wk   = (const float*)d_in[6];
    const float* Wv   = (const float*)d_in[7];
    const float* Wfc  = (const float*)d_in[8];
    const float* lnS  = (const float*)d_in[9];
    const float* lnB  = (const float*)d_in[10];
    float* out    = (float*)d_out;
    float* scores = out + OUT_ELEMS;
    unsigned short* wf = (unsigned short*)d_ws;   // 32KB of bf16 B-frags

    prep_w<<<4, 256, 0, stream>>>(Wq, Wk, Wv, Wfc, wf);
    mta_kernel<<<BN, 256, 0, stream>>>(Xq, Xk, Xv, msk, res, wf, lnS, lnB, out, scores);
}